// Round 2
// baseline (10753.289 us; speedup 1.0000x reference)
//
#include <hip/hip_runtime.h>

// DecoderRNN: 3-layer LSTM (H=1024) + fc, B=256, 128 steps, constant input.
// bf16 MFMA 16x16x32; gate-interleaved weight columns so the LSTM cell update
// is lane-local in the matmul epilogue; pipelined launches
// {L0(i), L1(i-1), L2(i-2), fc(i-3)} with parity-double-buffered h state.
// Reg-staging (global->reg->swizzled ds_write), 2-phase prefetch.

#define DEVINL static __device__ __forceinline__

typedef __bf16 bf16x8 __attribute__((ext_vector_type(8)));
typedef float f32x4 __attribute__((ext_vector_type(4)));
typedef unsigned short u16;
typedef unsigned int u32;

DEVINL u16 f2bf(float f) {
  u32 u = __builtin_bit_cast(u32, f);
  u += 0x7fffu + ((u >> 16) & 1u);  // RNE
  return (u16)(u >> 16);
}
DEVINL float sigm(float x) { return 1.0f / (1.0f + __expf(-x)); }
DEVINL float tanhfast(float x) { return 1.0f - 2.0f / (1.0f + __expf(2.0f * x)); }

// permuted column index -> original gate column: P = grp*64 + g*16 + jj
// maps hidden unit j = grp*16+jj, gate g  ->  orig n = g*1024 + j
DEVINL int permcol(int P) {
  int grp = P >> 6, g = (P >> 4) & 3, jj = P & 15;
  return g * 1024 + grp * 16 + jj;
}

struct Params {
  const float* fc_b;
  const float* inh_b;
  const float* inc_b;
  const u16 *WT0, *WT1, *WT2, *WT00, *FCW, *WIH, *WIC, *FRB;
  u16* HB;                            // h state bf16: [layer][parity][256][1024]
  float *G0P, *G0B, *B1P, *B2P, *CC;  // CC: c state fp32 [layer][256][1024]
  float* out;
};

#define MODE_L0 0
#define MODE_L 1
#define MODE_FC 2
#define MODE_G0 3
#define MODE_H 4
#define MODE_C 5

// Block: 256 threads, output tile 128(M) x 64(N). Waves stacked in M, each
// wave 32 rows x 64 cols = 2 M-frags x 4 N-frags of 16x16x32 MFMA.
// LDS tiles [rows][64 k] bf16, 128B rows; slot-XOR swizzle: LDS[row][slot ^
// (row&7)] holds global slot `slot` (slot = 8-elem granule of k).
template <int MODE>
DEVINL void mm_body(u16* Al, u16* Bl, const u16* A0, const u16* A1, int sA,
                    int kSplit, int K, const u16* Wt, int m0, int bn, int t,
                    const float* Gfull, const float* biasP, float* Cst,
                    u16* Hout, float* outp) {
  const int tid = threadIdx.x;
  const int l = tid & 63;
  const int w = tid >> 6;
  const int hh = (l >> 4) & 3;
  const int jj = l & 15;
  const int rl0 = w * 32 + jj;  // A row of m=0 frag (row&7 == l&7)
  const int e7 = l & 7;

  int rq[4], kq[4];
#pragma unroll
  for (int q = 0; q < 4; ++q) {
    int L = tid + q * 256;
    rq[q] = L >> 3;
    kq[q] = L & 7;
  }

  f32x4 acc[2][4];
#pragma unroll
  for (int m = 0; m < 2; ++m)
#pragma unroll
    for (int g = 0; g < 4; ++g) acc[m][g] = (f32x4){0.f, 0.f, 0.f, 0.f};

  const int wrow = bn * 64;  // B tile row base in WT
  uint4 av[4], bv[2];

  // prologue: issue loads for tile 0
  {
    const u16* Ab = (0 < kSplit) ? A0 : A1;
#pragma unroll
    for (int q = 0; q < 4; ++q)
      av[q] = *(const uint4*)(Ab + (size_t)(m0 + rq[q]) * sA + kq[q] * 8);
#pragma unroll
    for (int q = 0; q < 2; ++q)
      bv[q] = *(const uint4*)(Wt + (size_t)(wrow + rq[q]) * K + kq[q] * 8);
  }

  for (int k0 = 0; k0 < K; k0 += 64) {
    __syncthreads();  // previous tile's LDS readers done
#pragma unroll
    for (int q = 0; q < 4; ++q)
      *(uint4*)(Al + (rq[q] * 8 + (kq[q] ^ (rq[q] & 7))) * 8) = av[q];
#pragma unroll
    for (int q = 0; q < 2; ++q)
      *(uint4*)(Bl + (rq[q] * 8 + (kq[q] ^ (rq[q] & 7))) * 8) = bv[q];
    __syncthreads();
    int kn = k0 + 64;
    if (kn < K) {  // issue next tile's global loads before compute
      const u16* Ab = (kn < kSplit) ? (A0 + kn) : (A1 + (kn - kSplit));
#pragma unroll
      for (int q = 0; q < 4; ++q)
        av[q] = *(const uint4*)(Ab + (size_t)(m0 + rq[q]) * sA + kq[q] * 8);
      const u16* Bb = Wt + kn;
#pragma unroll
      for (int q = 0; q < 2; ++q)
        bv[q] = *(const uint4*)(Bb + (size_t)(wrow + rq[q]) * K + kq[q] * 8);
    }
#pragma unroll
    for (int kk = 0; kk < 2; ++kk) {
      int sl = (((kk << 2) | hh) ^ e7) * 8;
      bf16x8 a0 = *(const bf16x8*)(Al + rl0 * 64 + sl);
      bf16x8 a1 = *(const bf16x8*)(Al + (rl0 + 16) * 64 + sl);
      bf16x8 b0 = *(const bf16x8*)(Bl + (jj)*64 + sl);
      bf16x8 b1 = *(const bf16x8*)(Bl + (16 + jj) * 64 + sl);
      bf16x8 b2 = *(const bf16x8*)(Bl + (32 + jj) * 64 + sl);
      bf16x8 b3 = *(const bf16x8*)(Bl + (48 + jj) * 64 + sl);
      acc[0][0] = __builtin_amdgcn_mfma_f32_16x16x32_bf16(a0, b0, acc[0][0], 0, 0, 0);
      acc[0][1] = __builtin_amdgcn_mfma_f32_16x16x32_bf16(a0, b1, acc[0][1], 0, 0, 0);
      acc[0][2] = __builtin_amdgcn_mfma_f32_16x16x32_bf16(a0, b2, acc[0][2], 0, 0, 0);
      acc[0][3] = __builtin_amdgcn_mfma_f32_16x16x32_bf16(a0, b3, acc[0][3], 0, 0, 0);
      acc[1][0] = __builtin_amdgcn_mfma_f32_16x16x32_bf16(a1, b0, acc[1][0], 0, 0, 0);
      acc[1][1] = __builtin_amdgcn_mfma_f32_16x16x32_bf16(a1, b1, acc[1][1], 0, 0, 0);
      acc[1][2] = __builtin_amdgcn_mfma_f32_16x16x32_bf16(a1, b2, acc[1][2], 0, 0, 0);
      acc[1][3] = __builtin_amdgcn_mfma_f32_16x16x32_bf16(a1, b3, acc[1][3], 0, 0, 0);
    }
  }

  // C/D layout: col = lane&15, row = (lane>>4)*4 + reg  [m89-verified]
  const int rb = m0 + w * 32 + (hh << 2);
  if (MODE <= MODE_L) {
    float add0 = 0.f, add1 = 0.f, add2 = 0.f, add3 = 0.f;
    if (MODE == MODE_L) {
      add0 = biasP[bn * 64 + jj];
      add1 = biasP[bn * 64 + 16 + jj];
      add2 = biasP[bn * 64 + 32 + jj];
      add3 = biasP[bn * 64 + 48 + jj];
    }
    const int j = bn * 16 + jj;  // hidden unit
#pragma unroll
    for (int m = 0; m < 2; ++m) {
#pragma unroll
      for (int r = 0; r < 4; ++r) {
        int b = rb + m * 16 + r;
        float g0v, g1v, g2v, g3v;
        if (MODE == MODE_L0) {
          const float* G = Gfull + (size_t)b * 4096 + bn * 64 + jj;
          g0v = acc[m][0][r] + G[0];
          g1v = acc[m][1][r] + G[16];
          g2v = acc[m][2][r] + G[32];
          g3v = acc[m][3][r] + G[48];
        } else {
          g0v = acc[m][0][r] + add0;
          g1v = acc[m][1][r] + add1;
          g2v = acc[m][2][r] + add2;
          g3v = acc[m][3][r] + add3;
        }
        float iv = sigm(g0v), fv = sigm(g1v), gv = tanhfast(g2v), ov = sigm(g3v);
        size_t ci = (size_t)b * 1024 + j;
        float cn = fv * Cst[ci] + iv * gv;
        Cst[ci] = cn;
        Hout[ci] = f2bf(ov * tanhfast(cn));
      }
    }
  } else if (MODE == MODE_FC) {
#pragma unroll
    for (int g = 0; g < 4; ++g) {
      int n = bn * 64 + g * 16 + jj;
      if (n < 204) {
        float bv2 = biasP[n];
#pragma unroll
        for (int m = 0; m < 2; ++m)
#pragma unroll
          for (int r = 0; r < 4; ++r) {
            int b = rb + m * 16 + r;
            outp[((size_t)b * 128 + t) * 204 + n] = acc[m][g][r] + bv2;
          }
      }
    }
  } else if (MODE == MODE_G0) {
#pragma unroll
    for (int g = 0; g < 4; ++g) {
      int P = bn * 64 + g * 16 + jj;
      float bv2 = biasP[P];
#pragma unroll
      for (int m = 0; m < 2; ++m)
#pragma unroll
        for (int r = 0; r < 4; ++r) {
          int b = rb + m * 16 + r;
          outp[(size_t)b * 4096 + P] = acc[m][g][r] + bv2;
        }
    }
  } else {  // MODE_H / MODE_C : init states, cols are orig n = lay*1024 + j
#pragma unroll
    for (int g = 0; g < 4; ++g) {
      int n = bn * 64 + g * 16 + jj;
      int lay = n >> 10, j2 = n & 1023;
      float bv2 = biasP[n];
#pragma unroll
      for (int m = 0; m < 2; ++m)
#pragma unroll
        for (int r = 0; r < 4; ++r) {
          int b = rb + m * 16 + r;
          float v = acc[m][g][r] + bv2;
          if (MODE == MODE_H)
            Hout[(size_t)((lay * 2 + 1) * 256 + b) * 1024 + j2] = f2bf(v);
          else
            outp[(size_t)(lay * 256 + b) * 1024 + j2] = v;
        }
    }
  }
}

// Pipelined step: launch i runs {L0(i), L1(i-1), L2(i-2), fc(i-3)}
__global__ __launch_bounds__(256) void step_kernel(Params p, int i) {
  __shared__ u16 Al[128 * 64];
  __shared__ u16 Bl[64 * 64];
  int bid = blockIdx.x;
  int job = bid >> 7;  // 0..2 layers (128 blocks each), 384..391 -> 3 (fc)
  int t = i - job;
  if ((unsigned)t >= 128u) return;
  int par = t & 1, pv = par ^ 1;
  u16* HB = p.HB;
#define HBP(lay, pp) (HB + (size_t)(((lay)*2 + (pp)) * 256) * 1024)
  if (job == 0) {
    int lb = bid & 127;
    mm_body<MODE_L0>(Al, Bl, HBP(0, pv), nullptr, 1024, 1 << 30, 1024, p.WT0,
                     (lb >> 6) * 128, lb & 63, t, p.G0P, nullptr, p.CC,
                     HBP(0, par), nullptr);
  } else if (job == 1) {
    int lb = bid & 127;
    mm_body<MODE_L>(Al, Bl, HBP(0, par), HBP(1, pv), 1024, 1024, 2048, p.WT1,
                    (lb >> 6) * 128, lb & 63, t, nullptr, p.B1P,
                    p.CC + (size_t)256 * 1024, HBP(1, par), nullptr);
  } else if (job == 2) {
    int lb = bid & 127;
    mm_body<MODE_L>(Al, Bl, HBP(1, par), HBP(2, pv), 1024, 1024, 2048, p.WT2,
                    (lb >> 6) * 128, lb & 63, t, nullptr, p.B2P,
                    p.CC + (size_t)512 * 1024, HBP(2, par), nullptr);
  } else {
    int lb = bid - 384;  // 8 blocks: 2 M-tiles x 4 N-tiles (N padded 256)
    mm_body<MODE_FC>(Al, Bl, HBP(2, par), nullptr, 1024, 1 << 30, 1024, p.FCW,
                     (lb >> 2) * 128, lb & 3, t, nullptr, p.fc_b, nullptr,
                     nullptr, p.out);
  }
#undef HBP
}

// one-time: G0 = x_in@W_ih0+biases (permuted), h/c init = frame@in{h,c}_W + b
__global__ __launch_bounds__(256) void setup_mm(Params p) {
  __shared__ u16 Al[128 * 64];
  __shared__ u16 Bl[64 * 64];
  int bid = blockIdx.x;
  if (bid < 128) {
    mm_body<MODE_G0>(Al, Bl, p.FRB, nullptr, 256, 1 << 30, 256, p.WT00,
                     (bid >> 6) * 128, bid & 63, 0, nullptr, p.G0B, nullptr,
                     nullptr, p.G0P);
  } else if (bid < 224) {
    int b2 = bid - 128;
    mm_body<MODE_H>(Al, Bl, p.FRB, nullptr, 256, 1 << 30, 256, p.WIH,
                    (b2 / 48) * 128, b2 % 48, 0, nullptr, p.inh_b, nullptr,
                    p.HB, nullptr);
  } else {
    int b2 = bid - 224;
    mm_body<MODE_C>(Al, Bl, p.FRB, nullptr, 256, 1 << 30, 256, p.WIC,
                    (b2 / 48) * 128, b2 % 48, 0, nullptr, p.inc_b, nullptr,
                    nullptr, p.CC);
  }
}

// fp32 [K][N] sources -> bf16 transposed dst [Nout][Ktot] (K contiguous),
// optional gate permutation of output cols, zero pad k>=Kvalid / n>=Nvalid.
__global__ __launch_bounds__(256) void transpose_bf16(
    const float* __restrict__ srcA, const float* __restrict__ srcB,
    int srcStride, int kSplit, int Kvalid, int Nvalid, int perm,
    u16* __restrict__ dst, int Ktot) {
  __shared__ float tile[64][17];
  int P0 = blockIdx.x * 16;
  int k0 = blockIdx.y * 64;
  int t = threadIdx.x;
  int nl = t & 15;
  int kh = t >> 4;
  int P = P0 + nl;
  int n = perm ? permcol(P) : P;
  bool nok = (n < Nvalid);
#pragma unroll
  for (int q = 0; q < 4; ++q) {
    int kl = q * 16 + kh;
    int k = k0 + kl;
    float v = 0.f;
    if (nok && k < Kvalid) {
      const float* s = (k < kSplit) ? (srcA + (size_t)k * srcStride)
                                    : (srcB + (size_t)(k - kSplit) * srcStride);
      v = s[n];
    }
    tile[kl][nl] = v;
  }
  __syncthreads();
  int jo = t >> 4;
  int kb = (t & 15) << 2;
  unsigned long long pk =
      (unsigned long long)f2bf(tile[kb + 0][jo]) |
      ((unsigned long long)f2bf(tile[kb + 1][jo]) << 16) |
      ((unsigned long long)f2bf(tile[kb + 2][jo]) << 32) |
      ((unsigned long long)f2bf(tile[kb + 3][jo]) << 48);
  *(unsigned long long*)(dst + (size_t)(P0 + jo) * Ktot + k0 + kb) = pk;
}

__global__ __launch_bounds__(256) void build_frame(const float* __restrict__ inputs,
                                                   u16* __restrict__ FRB) {
  int id = blockIdx.x * 256 + threadIdx.x;  // 256*256
  int b = id >> 8, k = id & 255;
  FRB[id] = (k < 204) ? f2bf(inputs[b * 204 + k]) : (u16)0;
}

// G0 bias incl. one-hot label row; layer1/2 combined biases (permuted cols)
__global__ __launch_bounds__(256) void build_bias(
    const float* __restrict__ W_ih0, const float* __restrict__ b_ih0,
    const float* __restrict__ b_hh0, const float* __restrict__ b_ih1,
    const float* __restrict__ b_hh1, const float* __restrict__ b_ih2,
    const float* __restrict__ b_hh2, const int* __restrict__ labels,
    float* __restrict__ G0B, float* __restrict__ B1P, float* __restrict__ B2P) {
  int P = blockIdx.x * 256 + threadIdx.x;  // 4096
  int n = permcol(P);
  int lab = labels[0];
  G0B[P] = W_ih0[(size_t)(204 + lab) * 4096 + n] + b_ih0[n] + b_hh0[n];
  B1P[P] = b_ih1[n] + b_hh1[n];
  B2P[P] = b_ih2[n] + b_hh2[n];
}

extern "C" void kernel_launch(void* const* d_in, const int* in_sizes, int n_in,
                              void* d_out, int out_size, void* d_ws,
                              size_t ws_size, hipStream_t stream) {
  const float* inputs = (const float*)d_in[0];
  const float* W_ih0 = (const float*)d_in[1];
  const float* W_hh0 = (const float*)d_in[2];
  const float* b_ih0 = (const float*)d_in[3];
  const float* b_hh0 = (const float*)d_in[4];
  const float* W_ih1 = (const float*)d_in[5];
  const float* W_hh1 = (const float*)d_in[6];
  const float* b_ih1 = (const float*)d_in[7];
  const float* b_hh1 = (const float*)d_in[8];
  const float* W_ih2 = (const float*)d_in[9];
  const float* W_hh2 = (const float*)d_in[10];
  const float* b_ih2 = (const float*)d_in[11];
  const float* b_hh2 = (const float*)d_in[12];
  const float* fc_W = (const float*)d_in[13];
  const float* fc_b = (const float*)d_in[14];
  const float* inh_W = (const float*)d_in[15];
  const float* inh_b = (const float*)d_in[16];
  const float* inc_W = (const float*)d_in[17];
  const float* inc_b = (const float*)d_in[18];
  const int* labels = (const int*)d_in[19];

  char* ws = (char*)d_ws;
  size_t off = 0;
  auto alloc = [&](size_t bytes) {
    void* r = ws + off;
    off = (off + bytes + 255) & ~(size_t)255;
    return r;
  };
  u16* WT0 = (u16*)alloc(4096ull * 1024 * 2);
  u16* WT1 = (u16*)alloc(4096ull * 2048 * 2);
  u16* WT2 = (u16*)alloc(4096ull * 2048 * 2);
  u16* WT00 = (u16*)alloc(4096ull * 256 * 2);
  u16* FCW = (u16*)alloc(256ull * 1024 * 2);
  u16* WIH = (u16*)alloc(3072ull * 256 * 2);
  u16* WIC = (u16*)alloc(3072ull * 256 * 2);
  u16* FRB = (u16*)alloc(256ull * 256 * 2);
  u16* HB = (u16*)alloc(3ull * 2 * 256 * 1024 * 2);
  float* G0P = (float*)alloc(256ull * 4096 * 4);
  float* G0B = (float*)alloc(4096ull * 4);
  float* B1P = (float*)alloc(4096ull * 4);
  float* B2P = (float*)alloc(4096ull * 4);
  float* CC = (float*)alloc(3ull * 256 * 1024 * 4);
  if (off > ws_size) return;  // workspace too small: fail loudly (validation)

  const int BIG = 1 << 30;
  // weight repack (one-time per call)
  transpose_bf16<<<dim3(256, 16), 256, 0, stream>>>(W_hh0, nullptr, 4096, BIG, 1024, 4096, 1, WT0, 1024);
  transpose_bf16<<<dim3(256, 32), 256, 0, stream>>>(W_ih1, W_hh1, 4096, 1024, 2048, 4096, 1, WT1, 2048);
  transpose_bf16<<<dim3(256, 32), 256, 0, stream>>>(W_ih2, W_hh2, 4096, 1024, 2048, 4096, 1, WT2, 2048);
  transpose_bf16<<<dim3(256, 4), 256, 0, stream>>>(W_ih0, nullptr, 4096, BIG, 204, 4096, 1, WT00, 256);
  transpose_bf16<<<dim3(16, 16), 256, 0, stream>>>(fc_W, nullptr, 204, BIG, 1024, 204, 0, FCW, 1024);
  transpose_bf16<<<dim3(192, 4), 256, 0, stream>>>(inh_W, nullptr, 3072, BIG, 204, 3072, 0, WIH, 256);
  transpose_bf16<<<dim3(192, 4), 256, 0, stream>>>(inc_W, nullptr, 3072, BIG, 204, 3072, 0, WIC, 256);
  build_frame<<<256, 256, 0, stream>>>(inputs, FRB);
  build_bias<<<16, 256, 0, stream>>>(W_ih0, b_ih0, b_hh0, b_ih1, b_hh1, b_ih2,
                                     b_hh2, labels, G0B, B1P, B2P);

  Params p;
  p.fc_b = fc_b; p.inh_b = inh_b; p.inc_b = inc_b;
  p.WT0 = WT0; p.WT1 = WT1; p.WT2 = WT2; p.WT00 = WT00; p.FCW = FCW;
  p.WIH = WIH; p.WIC = WIC; p.FRB = FRB; p.HB = HB;
  p.G0P = G0P; p.G0B = G0B; p.B1P = B1P; p.B2P = B2P; p.CC = CC;
  p.out = (float*)d_out;

  setup_mm<<<320, 256, 0, stream>>>(p);

  // pipelined steps: i = 0..130
  for (int i = 0; i <= 130; ++i)
    step_kernel<<<392, 256, 0, stream>>>(p, i);
}